// Round 2
// baseline (890.784 us; speedup 1.0000x reference)
//
#include <hip/hip_runtime.h>
#include <hip/hip_bf16.h>

typedef unsigned short u16;
typedef __attribute__((ext_vector_type(8))) __bf16 bf16x8;
typedef __attribute__((ext_vector_type(4))) float f32x4;

#define LDSS 40  // LDS row stride in bf16 elems (32 data + 8 pad): 16B-aligned, max 2-way bank aliasing

__device__ __forceinline__ float bf2f(u16 u) {
    unsigned int x = ((unsigned int)u) << 16;
    return __builtin_bit_cast(float, x);
}
__device__ __forceinline__ u16 f2bf(float f) {
    unsigned int x = __builtin_bit_cast(unsigned int, f);
    unsigned int lsb = (x >> 16) & 1u;
    x += 0x7fffu + lsb;
    return (u16)(x >> 16);
}

// --- staging: load 8 contiguous elems from global, store 8 bf16 to LDS ------
__device__ __forceinline__ void ld8(u16* dst, const u16* src) {
    *(float4*)dst = *(const float4*)src;
}
__device__ __forceinline__ void ld8(u16* dst, const float* src) {
    float4 a = *(const float4*)src;
    float4 b = *(const float4*)(src + 4);
    u16 t[8];
    t[0] = f2bf(a.x); t[1] = f2bf(a.y); t[2] = f2bf(a.z); t[3] = f2bf(a.w);
    t[4] = f2bf(b.x); t[5] = f2bf(b.y); t[6] = f2bf(b.z); t[7] = f2bf(b.w);
    *(float4*)dst = *(float4*)t;
}
// --- epilogue store -----------------------------------------------------------
__device__ __forceinline__ void stC(u16* p, float v)   { *p = f2bf(v); }
__device__ __forceinline__ void stC(float* p, float v) { *p = v; }

// ---------------------------------------------------------------------------
// Generic NT GEMM: C[m,n] = sum_k A[m,k]*B[n,k] (+ bias[n]), fp32 acc.
// Grid: (Nn/128, M/128, batch). Block: 256 threads (4 waves, 2x2 of 64x64).
// ---------------------------------------------------------------------------
template <typename TA, typename TB, typename TC>
__global__ __launch_bounds__(256)
void gemm_nt(const TA* __restrict__ A, long long sA, int lda,
             const TB* __restrict__ B, long long sB, int ldb,
             TC* __restrict__ C, long long sC, int ldc,
             const float* __restrict__ bias, int K)
{
    __shared__ u16 As[128 * LDSS];
    __shared__ u16 Bs[128 * LDSS];

    const int tid = threadIdx.x;
    const int z = blockIdx.z;
    A += (long long)z * sA;
    B += (long long)z * sB;
    C += (long long)z * sC;
    const int m0 = blockIdx.y * 128;
    const int n0 = blockIdx.x * 128;
    const int wid = tid >> 6;
    const int lane = tid & 63;
    const int wm = (wid >> 1) * 64;
    const int wn = (wid & 1) * 64;
    const int lr = lane & 15;
    const int quad = lane >> 4;

    f32x4 acc[4][4];
#pragma unroll
    for (int i = 0; i < 4; i++)
#pragma unroll
        for (int j = 0; j < 4; j++)
#pragma unroll
            for (int r = 0; r < 4; r++) acc[i][j][r] = 0.f;

    const int srow = tid >> 2;          // 0..63
    const int scol = (tid & 3) * 8;     // 0,8,16,24

    for (int k0 = 0; k0 < K; k0 += 32) {
        __syncthreads();
        const TA* ga = A + (long long)(m0 + srow) * lda + k0 + scol;
        ld8(&As[srow * LDSS + scol], ga);
        ld8(&As[(srow + 64) * LDSS + scol], ga + (long long)64 * lda);
        const TB* gb = B + (long long)(n0 + srow) * ldb + k0 + scol;
        ld8(&Bs[srow * LDSS + scol], gb);
        ld8(&Bs[(srow + 64) * LDSS + scol], gb + (long long)64 * ldb);
        __syncthreads();

        bf16x8 af[4], bfr[4];
#pragma unroll
        for (int t = 0; t < 4; t++) {
            af[t]  = *(const bf16x8*)&As[(wm + t * 16 + lr) * LDSS + quad * 8];
            bfr[t] = *(const bf16x8*)&Bs[(wn + t * 16 + lr) * LDSS + quad * 8];
        }
#pragma unroll
        for (int i = 0; i < 4; i++)
#pragma unroll
            for (int j = 0; j < 4; j++)
                acc[i][j] = __builtin_amdgcn_mfma_f32_16x16x32_bf16(af[i], bfr[j], acc[i][j], 0, 0, 0);
    }

#pragma unroll
    for (int j = 0; j < 4; j++) {
        const int col = n0 + wn + j * 16 + lr;
        const float bv = bias ? bias[col] : 0.f;
#pragma unroll
        for (int i = 0; i < 4; i++) {
            const int rbase = m0 + wm + i * 16 + quad * 4;
#pragma unroll
            for (int r = 0; r < 4; r++)
                stC(&C[(long long)(rbase + r) * ldc + col], acc[i][j][r] + bv);
        }
    }
}

// ---------------------------------------------------------------------------
// Reorder y[B*N, 3*C] (bf16) -> q(scaled)/k/v as [B,H,N,HD], bf16.
// ---------------------------------------------------------------------------
__global__ __launch_bounds__(256)
void reorder_qkv(const u16* __restrict__ y, u16* __restrict__ q,
                 u16* __restrict__ k, u16* __restrict__ v)
{
    int t = blockIdx.x * 256 + threadIdx.x;   // 0 .. 1,572,864
    int which = t >> 19;
    int r = t & 524287;
    int d8 = r & 7;
    int n = (r >> 3) & 1023;
    int h = (r >> 13) & 15;
    int b = r >> 17;
    const u16* src = y + ((long long)(b * 1024 + n)) * 3072 + which * 1024 + h * 64 + d8 * 8;
    u16* dst = (which == 0 ? q : (which == 1 ? k : v)) +
               (((long long)((b * 16 + h) * 1024 + n)) * 64 + d8 * 8);
    float4 val = *(const float4*)src;
    if (which == 0) {
        u16 tmp[8];
        *(float4*)tmp = val;
#pragma unroll
        for (int i = 0; i < 8; i++) tmp[i] = f2bf(bf2f(tmp[i]) * 0.125f);  // HD^-0.5, exact pow2
        val = *(float4*)tmp;
    }
    *(float4*)dst = val;
}

// ---------------------------------------------------------------------------
// Talking-heads mix (pre) + softmax + mix (post). One block per (b,n).
// S: [B,H,N,N] bf16 logits (pre-mix). attn_out: [B,H,N,N] fp32 (output 1).
// Pexp kept in LDS as bf16 for the downstream AV GEMM consistency.
// ---------------------------------------------------------------------------
__global__ __launch_bounds__(256)
void mix_softmax(const u16* __restrict__ S, float* __restrict__ attn_out,
                 const float* __restrict__ wl, const float* __restrict__ bl,
                 const float* __restrict__ ww, const float* __restrict__ bw)
{
    __shared__ u16 P[16 * 1024];
    __shared__ float wlS[256];
    __shared__ float wwS[256];
    __shared__ float red[64];
    __shared__ float gmax[16];
    __shared__ float gsum[16];

    const int tid = threadIdx.x;
    const int lane = tid & 63;
    const int wid = tid >> 6;
    const int bn = blockIdx.x;
    const int b = bn >> 10, n = bn & 1023;

    wlS[tid] = wl[tid];
    const u16* Sb = S + ((long long)(b * 16) * 1024 + n) * 1024;
    for (int c = tid; c < 2048; c += 256) {
        int h = c >> 7;
        int mm = (c & 127) << 3;
        *(float4*)&P[h * 1024 + mm] = *(const float4*)(Sb + (long long)h * 1048576 + mm);
    }
    __syncthreads();

    float lv[4][16];
    float lmax[16], lsum[16];
#pragma unroll
    for (int g = 0; g < 16; g++) lmax[g] = -3.0e38f;

#pragma unroll
    for (int i = 0; i < 4; i++) {
        const int m = tid + i * 256;
        float sv[16];
#pragma unroll
        for (int h = 0; h < 16; h++) sv[h] = bf2f(P[h * 1024 + m]);
#pragma unroll
        for (int g = 0; g < 16; g++) {
            float a = bl[g];   // cancels in softmax, kept for fidelity
#pragma unroll
            for (int h = 0; h < 16; h++) a += wlS[g * 16 + h] * sv[h];
            lv[i][g] = a;
            lmax[g] = fmaxf(lmax[g], a);
        }
    }
#pragma unroll
    for (int g = 0; g < 16; g++) {
        float vv = lmax[g];
        for (int off = 32; off; off >>= 1) vv = fmaxf(vv, __shfl_xor(vv, off, 64));
        if (lane == 0) red[wid * 16 + g] = vv;
    }
    __syncthreads();
    if (tid < 16) gmax[tid] = fmaxf(fmaxf(red[tid], red[16 + tid]), fmaxf(red[32 + tid], red[48 + tid]));
    __syncthreads();

#pragma unroll
    for (int g = 0; g < 16; g++) lsum[g] = 0.f;
#pragma unroll
    for (int i = 0; i < 4; i++) {
        const int m = tid + i * 256;
#pragma unroll
        for (int g = 0; g < 16; g++) {
            float p = __expf(lv[i][g] - gmax[g]);
            lsum[g] += p;
            P[g * 1024 + m] = f2bf(p);
        }
    }
#pragma unroll
    for (int g = 0; g < 16; g++) {
        float vv = lsum[g];
        for (int off = 32; off; off >>= 1) vv += __shfl_xor(vv, off, 64);
        if (lane == 0) red[wid * 16 + g] = vv;
    }
    __syncthreads();
    if (tid < 16) gsum[tid] = red[tid] + red[16 + tid] + red[32 + tid] + red[48 + tid];
    __syncthreads();
    wwS[tid] = ww[tid] / gsum[tid & 15];   // wwS[g*16+h] = ww[g,h]/L[h]
    __syncthreads();

#pragma unroll
    for (int i = 0; i < 4; i++) {
        const int m = tid + i * 256;
        float pv[16];
#pragma unroll
        for (int h = 0; h < 16; h++) pv[h] = bf2f(P[h * 1024 + m]);
#pragma unroll
        for (int g = 0; g < 16; g++) {
            float a = bw[g];
#pragma unroll
            for (int h = 0; h < 16; h++) a += wwS[g * 16 + h] * pv[h];
            attn_out[((long long)((b * 16 + g) * 1024 + n)) * 1024 + m] = a;
        }
    }
}

// ---------------------------------------------------------------------------
// out1[b*1024+n, h*64+d] = sum_m attn[b,h,n,m] * v[b,h,m,d]
// attn fp32 (from d_out), v bf16 (ws), out1 bf16 (ws).
// Grid: (8, 1, 64). Block 256 (4 waves, each 32 rows x 64 cols).
// ---------------------------------------------------------------------------
__global__ __launch_bounds__(256)
void av_gemm(const float* __restrict__ attn, const u16* __restrict__ v,
             u16* __restrict__ out1)
{
    __shared__ u16 As[128 * LDSS];
    __shared__ u16 Bs[64 * LDSS];

    const int tid = threadIdx.x;
    const int z = blockIdx.z;   // b*16+h
    const int b = z >> 4, h = z & 15;
    const int m0 = blockIdx.x * 128;
    const float* Ab = attn + (long long)z * 1048576;
    const u16* Vb = v + (long long)z * 65536;
    const int wid = tid >> 6;
    const int lane = tid & 63;
    const int lr = lane & 15;
    const int quad = lane >> 4;
    const int wm = wid * 32;

    f32x4 acc[2][4];
#pragma unroll
    for (int i = 0; i < 2; i++)
#pragma unroll
        for (int j = 0; j < 4; j++)
#pragma unroll
            for (int r = 0; r < 4; r++) acc[i][j][r] = 0.f;

    const int srow = tid >> 2;
    const int scol = (tid & 3) * 8;
    const int vrow = tid >> 3;        // 0..31 (m within tile)
    const int vdb = (tid & 7) * 8;    // d base

    for (int k0 = 0; k0 < 1024; k0 += 32) {
        __syncthreads();
        const float* ga = Ab + (long long)(m0 + srow) * 1024 + k0 + scol;
        ld8(&As[srow * LDSS + scol], ga);
        ld8(&As[(srow + 64) * LDSS + scol], ga + 64 * 1024);
        u16 tmp[8];
        *(float4*)tmp = *(const float4*)(Vb + (long long)(k0 + vrow) * 64 + vdb);
#pragma unroll
        for (int j = 0; j < 8; j++) Bs[(vdb + j) * LDSS + vrow] = tmp[j];
        __syncthreads();

        bf16x8 af[2], bfr[4];
#pragma unroll
        for (int t = 0; t < 2; t++)
            af[t] = *(const bf16x8*)&As[(wm + t * 16 + lr) * LDSS + quad * 8];
#pragma unroll
        for (int t = 0; t < 4; t++)
            bfr[t] = *(const bf16x8*)&Bs[(t * 16 + lr) * LDSS + quad * 8];
#pragma unroll
        for (int i = 0; i < 2; i++)
#pragma unroll
            for (int j = 0; j < 4; j++)
                acc[i][j] = __builtin_amdgcn_mfma_f32_16x16x32_bf16(af[i], bfr[j], acc[i][j], 0, 0, 0);
    }

#pragma unroll
    for (int j = 0; j < 4; j++) {
        const int col = h * 64 + j * 16 + lr;
#pragma unroll
        for (int i = 0; i < 2; i++) {
            const int rbase = m0 + wm + i * 16 + quad * 4;
#pragma unroll
            for (int r = 0; r < 4; r++)
                out1[(long long)(b * 1024 + rbase + r) * 1024 + col] = f2bf(acc[i][j][r]);
        }
    }
}

// ---------------------------------------------------------------------------
extern "C" void kernel_launch(void* const* d_in, const int* in_sizes, int n_in,
                              void* d_out, int out_size, void* d_ws, size_t ws_size,
                              hipStream_t stream)
{
    const float* x      = (const float*)d_in[0];
    const float* qkv_w  = (const float*)d_in[1];
    const float* qkv_b  = (const float*)d_in[2];
    const float* proj_w = (const float*)d_in[3];
    const float* proj_b = (const float*)d_in[4];
    const float* wl     = (const float*)d_in[5];
    const float* bl     = (const float*)d_in[6];
    const float* ww     = (const float*)d_in[7];
    const float* bw     = (const float*)d_in[8];

    float* out      = (float*)d_out;            // [B,N,C] = 4,194,304 fp32
    float* attn_out = out + 4194304;            // [B,H,N,N] = 16,777,216 fp32

    u16* ws   = (u16*)d_ws;
    u16* y    = ws;                // 12,582,912 elems (qkv raw, bf16)
    u16* q    = ws + 12582912;     //  4,194,304
    u16* k    = ws + 16777216;     //  4,194,304
    u16* v    = ws + 20971520;     //  4,194,304
    u16* s    = ws + 25165824;     // 16,777,216 (pre-mix logits, bf16)
    u16* out1 = ws;                // reuse y region (dead after reorder)

    dim3 blk(256);
    // K1: qkv = x @ qkv_w^T + qkv_b   [4096 x 3072 x 1024], fp32 in -> bf16 out
    gemm_nt<float, float, u16><<<dim3(24, 32, 1), blk, 0, stream>>>(
        x, 0, 1024, qkv_w, 0, 1024, y, 0, 3072, qkv_b, 1024);
    // K2: split/scale into q,k,v [B,H,N,HD] bf16
    reorder_qkv<<<dim3(6144), blk, 0, stream>>>(y, q, k, v);
    // K3: per-head scores = q @ k^T  [1024 x 1024 x 64] x 64 heads, bf16
    gemm_nt<u16, u16, u16><<<dim3(8, 8, 64), blk, 0, stream>>>(
        q, 65536, 64, k, 65536, 64, s, 1048576, 1024, nullptr, 64);
    // K4: talking-heads mix + softmax + mix -> attn output (fp32, d_out)
    mix_softmax<<<dim3(4096), blk, 0, stream>>>(s, attn_out, wl, bl, ww, bw);
    // K5: out1 = attn @ v, scattered to [B,N,C] bf16
    av_gemm<<<dim3(8, 1, 64), blk, 0, stream>>>(attn_out, v, out1);
    // K6: out = out1 @ proj_w^T + proj_b  [4096 x 1024 x 1024], fp32 out
    gemm_nt<u16, float, float><<<dim3(8, 32, 1), blk, 0, stream>>>(
        out1, 0, 1024, proj_w, 0, 1024, out, 0, 1024, proj_b, 1024);
}

// Round 3
// 732.502 us; speedup vs baseline: 1.2161x; 1.2161x over previous
//
#include <hip/hip_runtime.h>
#include <hip/hip_bf16.h>

typedef unsigned short u16;
typedef __attribute__((ext_vector_type(8))) __bf16 bf16x8;
typedef __attribute__((ext_vector_type(4))) float f32x4;

#define LDSS 40  // LDS row stride in bf16 elems (32 data + 8 pad): 16B-aligned, max 2-way bank aliasing

__device__ __forceinline__ float bf2f(u16 u) {
    unsigned int x = ((unsigned int)u) << 16;
    return __builtin_bit_cast(float, x);
}
__device__ __forceinline__ u16 f2bf(float f) {
    unsigned int x = __builtin_bit_cast(unsigned int, f);
    unsigned int lsb = (x >> 16) & 1u;
    x += 0x7fffu + lsb;
    return (u16)(x >> 16);
}

// --- staging: load 8 contiguous elems from global, store 8 bf16 to LDS ------
__device__ __forceinline__ void ld8(u16* dst, const u16* src) {
    *(float4*)dst = *(const float4*)src;
}
__device__ __forceinline__ void ld8(u16* dst, const float* src) {
    float4 a = *(const float4*)src;
    float4 b = *(const float4*)(src + 4);
    u16 t[8];
    t[0] = f2bf(a.x); t[1] = f2bf(a.y); t[2] = f2bf(a.z); t[3] = f2bf(a.w);
    t[4] = f2bf(b.x); t[5] = f2bf(b.y); t[6] = f2bf(b.z); t[7] = f2bf(b.w);
    *(float4*)dst = *(float4*)t;
}
__device__ __forceinline__ void stC(u16* p, float v)   { *p = f2bf(v); }
__device__ __forceinline__ void stC(float* p, float v) { *p = v; }

// ---------------------------------------------------------------------------
// Generic NT GEMM: C[m,n] = sum_k A[m,k]*B[n,k] (+ bias[n]), fp32 acc.
// Grid: (Nn/128, M/128, batch). Block: 256 threads (4 waves, 2x2 of 64x64).
// ---------------------------------------------------------------------------
template <typename TA, typename TB, typename TC>
__global__ __launch_bounds__(256)
void gemm_nt(const TA* __restrict__ A, long long sA, int lda,
             const TB* __restrict__ B, long long sB, int ldb,
             TC* __restrict__ C, long long sC, int ldc,
             const float* __restrict__ bias, int K)
{
    __shared__ u16 As[128 * LDSS];
    __shared__ u16 Bs[128 * LDSS];

    const int tid = threadIdx.x;
    const int z = blockIdx.z;
    A += (long long)z * sA;
    B += (long long)z * sB;
    C += (long long)z * sC;
    const int m0 = blockIdx.y * 128;
    const int n0 = blockIdx.x * 128;
    const int wid = tid >> 6;
    const int lane = tid & 63;
    const int wm = (wid >> 1) * 64;
    const int wn = (wid & 1) * 64;
    const int lr = lane & 15;
    const int quad = lane >> 4;

    f32x4 acc[4][4];
#pragma unroll
    for (int i = 0; i < 4; i++)
#pragma unroll
        for (int j = 0; j < 4; j++)
#pragma unroll
            for (int r = 0; r < 4; r++) acc[i][j][r] = 0.f;

    const int srow = tid >> 2;          // 0..63
    const int scol = (tid & 3) * 8;     // 0,8,16,24

    for (int k0 = 0; k0 < K; k0 += 32) {
        __syncthreads();
        const TA* ga = A + (long long)(m0 + srow) * lda + k0 + scol;
        ld8(&As[srow * LDSS + scol], ga);
        ld8(&As[(srow + 64) * LDSS + scol], ga + (long long)64 * lda);
        const TB* gb = B + (long long)(n0 + srow) * ldb + k0 + scol;
        ld8(&Bs[srow * LDSS + scol], gb);
        ld8(&Bs[(srow + 64) * LDSS + scol], gb + (long long)64 * ldb);
        __syncthreads();

        bf16x8 af[4], bfr[4];
#pragma unroll
        for (int t = 0; t < 4; t++) {
            af[t]  = *(const bf16x8*)&As[(wm + t * 16 + lr) * LDSS + quad * 8];
            bfr[t] = *(const bf16x8*)&Bs[(wn + t * 16 + lr) * LDSS + quad * 8];
        }
#pragma unroll
        for (int i = 0; i < 4; i++)
#pragma unroll
            for (int j = 0; j < 4; j++)
                acc[i][j] = __builtin_amdgcn_mfma_f32_16x16x32_bf16(af[i], bfr[j], acc[i][j], 0, 0, 0);
    }

#pragma unroll
    for (int j = 0; j < 4; j++) {
        const int col = n0 + wn + j * 16 + lr;
        const float bv = bias ? bias[col] : 0.f;
#pragma unroll
        for (int i = 0; i < 4; i++) {
            const int rbase = m0 + wm + i * 16 + quad * 4;
#pragma unroll
            for (int r = 0; r < 4; r++)
                stC(&C[(long long)(rbase + r) * ldc + col], acc[i][j][r] + bv);
        }
    }
}

// ---------------------------------------------------------------------------
// Reorder y[B*N, 3*C] (bf16) -> q(scaled)/k/v as [B,H,N,HD], bf16.
// ---------------------------------------------------------------------------
__global__ __launch_bounds__(256)
void reorder_qkv(const u16* __restrict__ y, u16* __restrict__ q,
                 u16* __restrict__ k, u16* __restrict__ v)
{
    int t = blockIdx.x * 256 + threadIdx.x;
    int which = t >> 19;
    int r = t & 524287;
    int d8 = r & 7;
    int n = (r >> 3) & 1023;
    int h = (r >> 13) & 15;
    int b = r >> 17;
    const u16* src = y + ((long long)(b * 1024 + n)) * 3072 + which * 1024 + h * 64 + d8 * 8;
    u16* dst = (which == 0 ? q : (which == 1 ? k : v)) +
               (((long long)((b * 16 + h) * 1024 + n)) * 64 + d8 * 8);
    float4 val = *(const float4*)src;
    if (which == 0) {
        u16 tmp[8];
        *(float4*)tmp = val;
#pragma unroll
        for (int i = 0; i < 8; i++) tmp[i] = f2bf(bf2f(tmp[i]) * 0.125f);  // HD^-0.5, exact pow2
        val = *(float4*)tmp;
    }
    *(float4*)dst = val;
}

// ---------------------------------------------------------------------------
// Talking-heads mix (pre) + softmax + mix (post). One block per (b,n).
// Register-resident: no LDS data tile. Thread t owns m = 4t..4t+3.
// S bf16 [B,H,N,N]; writes fp32 attn (d_out) and bf16 attn IN PLACE over S
// (safe: each (h,n,m) location read & written by the same thread, read first).
// ---------------------------------------------------------------------------
__global__ __launch_bounds__(256)
void mix_softmax(const u16* __restrict__ S, float* __restrict__ attn_out,
                 u16* __restrict__ attn_bf,
                 const float* __restrict__ wl, const float* __restrict__ bl,
                 const float* __restrict__ ww, const float* __restrict__ bw)
{
    __shared__ float wlS[256];
    __shared__ float wwS[256];
    __shared__ float blS[16];
    __shared__ float bwS[16];
    __shared__ float red[64];
    __shared__ float gmax[16];
    __shared__ float gsum[16];

    const int tid = threadIdx.x;
    const int lane = tid & 63;
    const int wid = tid >> 6;
    const int b = blockIdx.x >> 10, n = blockIdx.x & 1023;
    const int m0 = tid * 4;

    wlS[tid] = wl[tid];
    if (tid < 16) { blS[tid] = bl[tid]; bwS[tid] = bw[tid]; }

    // load S[h, n, m0..m0+3] for all 16 h -> registers (8B coalesced per h)
    const long long base = ((long long)(b * 16) * 1024 + n) * 1024 + m0;
    float sv[16][4];
#pragma unroll
    for (int h = 0; h < 16; h++) {
        ushort4 r = *(const ushort4*)(S + base + (long long)h * 1048576);
        sv[h][0] = bf2f(r.x); sv[h][1] = bf2f(r.y);
        sv[h][2] = bf2f(r.z); sv[h][3] = bf2f(r.w);
    }
    __syncthreads();

    // pre-mix: a[g][j] = bl[g] + sum_h wl[g,h] * sv[h][j]
    float a[16][4];
    float lmax[16];
#pragma unroll
    for (int g = 0; g < 16; g++) {
        float4 w0 = *(const float4*)&wlS[g * 16];
        float4 w1 = *(const float4*)&wlS[g * 16 + 4];
        float4 w2 = *(const float4*)&wlS[g * 16 + 8];
        float4 w3 = *(const float4*)&wlS[g * 16 + 12];
        const float* wp = (const float*)&w0;  // w0..w3 contiguous? no - use array
        float wr[16];
        *(float4*)&wr[0] = w0; *(float4*)&wr[4] = w1;
        *(float4*)&wr[8] = w2; *(float4*)&wr[12] = w3;
        float a0 = blS[g], a1 = a0, a2 = a0, a3 = a0;
#pragma unroll
        for (int h = 0; h < 16; h++) {
            a0 += wr[h] * sv[h][0];
            a1 += wr[h] * sv[h][1];
            a2 += wr[h] * sv[h][2];
            a3 += wr[h] * sv[h][3];
        }
        a[g][0] = a0; a[g][1] = a1; a[g][2] = a2; a[g][3] = a3;
        lmax[g] = fmaxf(fmaxf(a0, a1), fmaxf(a2, a3));
        (void)wp;
    }

    // per-head max across block
#pragma unroll
    for (int g = 0; g < 16; g++) {
        float vv = lmax[g];
        for (int off = 32; off; off >>= 1) vv = fmaxf(vv, __shfl_xor(vv, off, 64));
        if (lane == 0) red[wid * 16 + g] = vv;
    }
    __syncthreads();
    if (tid < 16) gmax[tid] = fmaxf(fmaxf(red[tid], red[16 + tid]), fmaxf(red[32 + tid], red[48 + tid]));
    __syncthreads();

    // exp in place, accumulate sums
    float lsum[16];
#pragma unroll
    for (int g = 0; g < 16; g++) {
        float mg = gmax[g];
        float p0 = __expf(a[g][0] - mg);
        float p1 = __expf(a[g][1] - mg);
        float p2 = __expf(a[g][2] - mg);
        float p3 = __expf(a[g][3] - mg);
        a[g][0] = p0; a[g][1] = p1; a[g][2] = p2; a[g][3] = p3;
        lsum[g] = (p0 + p1) + (p2 + p3);
    }
#pragma unroll
    for (int g = 0; g < 16; g++) {
        float vv = lsum[g];
        for (int off = 32; off; off >>= 1) vv += __shfl_xor(vv, off, 64);
        if (lane == 0) red[wid * 16 + g] = vv;
    }
    __syncthreads();
    if (tid < 16) gsum[tid] = red[tid] + red[16 + tid] + red[32 + tid] + red[48 + tid];
    __syncthreads();
    wwS[tid] = ww[tid] / gsum[tid & 15];   // wwS[g*16+h] = ww[g,h]/L[h]
    __syncthreads();

    // post-mix + store (fp32 to d_out, bf16 in place over S)
#pragma unroll
    for (int g = 0; g < 16; g++) {
        float wr[16];
        *(float4*)&wr[0]  = *(const float4*)&wwS[g * 16];
        *(float4*)&wr[4]  = *(const float4*)&wwS[g * 16 + 4];
        *(float4*)&wr[8]  = *(const float4*)&wwS[g * 16 + 8];
        *(float4*)&wr[12] = *(const float4*)&wwS[g * 16 + 12];
        float o0 = bwS[g], o1 = o0, o2 = o0, o3 = o0;
#pragma unroll
        for (int h = 0; h < 16; h++) {
            o0 += wr[h] * a[h][0];
            o1 += wr[h] * a[h][1];
            o2 += wr[h] * a[h][2];
            o3 += wr[h] * a[h][3];
        }
        const long long off = base + (long long)g * 1048576;
        float4 fo; fo.x = o0; fo.y = o1; fo.z = o2; fo.w = o3;
        *(float4*)(attn_out + off) = fo;
        ushort4 bo;
        bo.x = f2bf(o0); bo.y = f2bf(o1); bo.z = f2bf(o2); bo.w = f2bf(o3);
        *(ushort4*)(attn_bf + off) = bo;
    }
}

// ---------------------------------------------------------------------------
// out1[b*1024+n, h*64+d] = sum_m attn_bf[b,h,n,m] * v[b,h,m,d], all bf16.
// Grid: (16, 1, 64). Block 256 = 4 waves; each wave 16 rows x 64 cols.
// ---------------------------------------------------------------------------
__global__ __launch_bounds__(256)
void av_gemm(const u16* __restrict__ attn_bf, const u16* __restrict__ v,
             u16* __restrict__ out1)
{
    __shared__ u16 As[64 * LDSS];
    __shared__ u16 Bs[64 * LDSS];

    const int tid = threadIdx.x;
    const int z = blockIdx.z;   // b*16+h
    const int b = z >> 4, h = z & 15;
    const int m0 = blockIdx.x * 64;
    const u16* Ab = attn_bf + (long long)z * 1048576;
    const u16* Vb = v + (long long)z * 65536;
    const int wid = tid >> 6;
    const int lane = tid & 63;
    const int lr = lane & 15;
    const int quad = lane >> 4;
    const int wm = wid * 16;

    f32x4 acc[4];
#pragma unroll
    for (int j = 0; j < 4; j++)
#pragma unroll
        for (int r = 0; r < 4; r++) acc[j][r] = 0.f;

    const int srow = tid >> 2;        // 0..63
    const int scol = (tid & 3) * 8;
    const int vrow = tid >> 3;        // 0..31 (m within k-tile)
    const int vdb = (tid & 7) * 8;    // d base

    for (int k0 = 0; k0 < 1024; k0 += 32) {
        __syncthreads();
        *(float4*)&As[srow * LDSS + scol] =
            *(const float4*)(Ab + (long long)(m0 + srow) * 1024 + k0 + scol);
        u16 tmp[8];
        *(float4*)tmp = *(const float4*)(Vb + (long long)(k0 + vrow) * 64 + vdb);
#pragma unroll
        for (int j = 0; j < 8; j++) Bs[(vdb + j) * LDSS + vrow] = tmp[j];
        __syncthreads();

        bf16x8 af, bfr[4];
        af = *(const bf16x8*)&As[(wm + lr) * LDSS + quad * 8];
#pragma unroll
        for (int t = 0; t < 4; t++)
            bfr[t] = *(const bf16x8*)&Bs[(t * 16 + lr) * LDSS + quad * 8];
#pragma unroll
        for (int j = 0; j < 4; j++)
            acc[j] = __builtin_amdgcn_mfma_f32_16x16x32_bf16(af, bfr[j], acc[j], 0, 0, 0);
    }

#pragma unroll
    for (int j = 0; j < 4; j++) {
        const int col = h * 64 + j * 16 + lr;
        const int rbase = m0 + wm + quad * 4;
#pragma unroll
        for (int r = 0; r < 4; r++)
            out1[(long long)(b * 1024 + rbase + r) * 1024 + col] = f2bf(acc[j][r]);
    }
}

// ---------------------------------------------------------------------------
extern "C" void kernel_launch(void* const* d_in, const int* in_sizes, int n_in,
                              void* d_out, int out_size, void* d_ws, size_t ws_size,
                              hipStream_t stream)
{
    const float* x      = (const float*)d_in[0];
    const float* qkv_w  = (const float*)d_in[1];
    const float* qkv_b  = (const float*)d_in[2];
    const float* proj_w = (const float*)d_in[3];
    const float* proj_b = (const float*)d_in[4];
    const float* wl     = (const float*)d_in[5];
    const float* bl     = (const float*)d_in[6];
    const float* ww     = (const float*)d_in[7];
    const float* bw     = (const float*)d_in[8];

    float* out      = (float*)d_out;            // [B,N,C] fp32
    float* attn_out = out + 4194304;            // [B,H,N,N] fp32

    u16* ws   = (u16*)d_ws;
    u16* y    = ws;                // 12,582,912 (qkv raw, bf16)
    u16* q    = ws + 12582912;     //  4,194,304
    u16* k    = ws + 16777216;     //  4,194,304
    u16* v    = ws + 20971520;     //  4,194,304
    u16* s    = ws + 25165824;     // 16,777,216 (pre-mix logits; attn_bf aliases it)
    u16* out1 = ws;                // reuse y region (dead after reorder)

    dim3 blk(256);
    // K1: qkv = x @ qkv_w^T + qkv_b   [4096 x 3072 x 1024], fp32 in -> bf16 out
    gemm_nt<float, float, u16><<<dim3(24, 32, 1), blk, 0, stream>>>(
        x, 0, 1024, qkv_w, 0, 1024, y, 0, 3072, qkv_b, 1024);
    // K2: split/scale into q,k,v [B,H,N,HD] bf16
    reorder_qkv<<<dim3(6144), blk, 0, stream>>>(y, q, k, v);
    // K3: per-head scores = q @ k^T  [1024 x 1024 x 64] x 64 heads, bf16
    gemm_nt<u16, u16, u16><<<dim3(8, 8, 64), blk, 0, stream>>>(
        q, 65536, 64, k, 65536, 64, s, 1048576, 1024, nullptr, 64);
    // K4: talking-heads mix + softmax + mix; fp32 attn to d_out, bf16 in place
    mix_softmax<<<dim3(4096), blk, 0, stream>>>(s, attn_out, s, wl, bl, ww, bw);
    // K5: out1 = attn_bf @ v, scattered to [B,N,C] bf16
    av_gemm<<<dim3(16, 1, 64), blk, 0, stream>>>(s, v, out1);
    // K6: out = out1 @ proj_w^T + proj_b  [4096 x 1024 x 1024], fp32 out
    gemm_nt<u16, float, float><<<dim3(8, 32, 1), blk, 0, stream>>>(
        out1, 0, 1024, proj_w, 0, 1024, out, 0, 1024, proj_b, 1024);
}